// Round 5
// baseline (985.069 us; speedup 1.0000x reference)
//
#include <hip/hip_runtime.h>
#include <hip/hip_bf16.h>

// GCN fused pipeline for MI355X — bucket-grouped edge records, no CSR.
// vocab=1 => h1[i] = relu(embW1*c_i + b1), piecewise-linear in scalar c_i.
// g[i][d] = a_i*P[bin_i][d] + b_i*Q[bin_i][d]; per-edge payload = (a,b,bin).
// Edges grouped into 782 buckets of 128 dst nodes; pass-2 accumulates in LDS.
// Inputs: 0 x[int32 N], 1 edge_index[int32 2*E] (src then dst), 2 batch[int32 N sorted],
// 3 emb[1*64], 4 W1[64*64], 5 b1[64], 6 W2[64*64], 7 b2[64], 8 fcW[64*32], 9 fcb[32].
// Output: [G=64, 32] fp32.

#define DH 64
#define DOUT 32
#define NBIN 65
#define BW 128        // bucket node width
#define MAXNB 1024    // max buckets (N <= 131072)
#define P1B 128       // pass-1 blocks

__global__ void k_count(const int* __restrict__ dst, int* __restrict__ counts, int E) {
    int e = blockIdx.x * blockDim.x + threadIdx.x;
    if (e < E) atomicAdd(&counts[dst[e]], 1);
}

__global__ void k_dinv(const int* __restrict__ counts, float* __restrict__ dinv, int N) {
    int i = blockIdx.x * blockDim.x + threadIdx.x;
    if (i < N) dinv[i] = rsqrtf((float)counts[i] + 1.0f);
}

__global__ void k_S(const int* __restrict__ src, const int* __restrict__ dst,
                    const float* __restrict__ dinv, float* __restrict__ S, int E) {
    int e = blockIdx.x * blockDim.x + threadIdx.x;
    if (e < E) atomicAdd(&S[dst[e]], dinv[src[e]]);
}

// ---- embW1, hinge breakpoints t_k, ranks r_k = #{t<=t_k}, s_k = #{t<t_k} ----
__global__ void k_prep(const float* __restrict__ emb, const float* __restrict__ W1,
                       const float* __restrict__ b1, float* __restrict__ ew,
                       float* __restrict__ tarr, int* __restrict__ rarr,
                       int* __restrict__ sarr) {
    __shared__ float tl[DH];
    int k = threadIdx.x;  // 64 threads
    float s = 0.f;
#pragma unroll
    for (int j = 0; j < DH; ++j) s += emb[j] * W1[j * DH + k];
    float t = (s != 0.f) ? (-b1[k] / s) : INFINITY;
    tl[k] = t;
    ew[k] = s;
    tarr[k] = t;
    __syncthreads();
    int r = 0, ss = 0;
#pragma unroll
    for (int j = 0; j < DH; ++j) { r += (tl[j] <= t); ss += (tl[j] < t); }
    rarr[k] = r;
    sarr[k] = ss;
}

// ---- PQ[beta*DH+d] = (P,Q) prefix tables over ReLU active sets ----
__global__ void k_tables(const float* __restrict__ ew, const float* __restrict__ b1,
                         const float* __restrict__ W2, const int* __restrict__ rarr,
                         const int* __restrict__ sarr, float2* __restrict__ PQ) {
    int beta = blockIdx.x;   // 0..64
    int d = threadIdx.x;     // 0..63
    float p = 0.f, q = 0.f;
    for (int k = 0; k < DH; ++k) {
        float e = ew[k];
        bool act;
        if (e > 0.f) act = (beta >= rarr[k]);
        else if (e < 0.f) act = (beta <= sarr[k]);
        else act = (b1[k] > 0.f);
        if (act) {
            float w = W2[k * DH + d];
            p += e * w;
            q += b1[k] * w;
        }
    }
    PQ[beta * DH + d] = make_float2(p, q);
}

// ---- per-node summary (a_i, b_i, bin_i) — pure elementwise now ----
__global__ void k_node2(const float* __restrict__ dinv, const float* __restrict__ S,
                        const float* __restrict__ tarr, float4* __restrict__ summary, int N) {
    __shared__ float tl[DH];
    if (threadIdx.x < DH) tl[threadIdx.x] = tarr[threadIdx.x];
    __syncthreads();
    int i = blockIdx.x * blockDim.x + threadIdx.x;
    if (i >= N) return;
    float di = dinv[i];
    float c = di * (S[i] + di);
    int b = 0;
#pragma unroll
    for (int j = 0; j < DH; ++j) b += (tl[j] < c);
    summary[i] = make_float4(di * c, di, __uint_as_float((unsigned)b), 0.f);
}

// ---- bucket histogram (per-block LDS, then one global add per bucket) ----
__global__ void k_bhist(const int* __restrict__ dst, int* __restrict__ bhist,
                        int E, int NB) {
    __shared__ int lh[MAXNB];
    for (int t = threadIdx.x; t < NB; t += blockDim.x) lh[t] = 0;
    __syncthreads();
    for (int e = blockIdx.x * blockDim.x + threadIdx.x; e < E; e += gridDim.x * blockDim.x)
        atomicAdd(&lh[dst[e] >> 7], 1);
    __syncthreads();
    for (int t = threadIdx.x; t < NB; t += blockDim.x)
        if (lh[t]) atomicAdd(&bhist[t], lh[t]);
}

// ---- exclusive scan of bucket counts -> base, cursor ----
__global__ void k_bscan(const int* __restrict__ bhist, int* __restrict__ base,
                        int* __restrict__ cursor, int NB, int E) {
    __shared__ int tmp[MAXNB];
    int t = threadIdx.x;  // 1024
    int v = (t < NB) ? bhist[t] : 0;
    tmp[t] = v;
    __syncthreads();
    for (int off = 1; off < MAXNB; off <<= 1) {
        int u = (t >= off) ? tmp[t - off] : 0;
        __syncthreads();
        tmp[t] += u;
        __syncthreads();
    }
    if (t < NB) { int ex = tmp[t] - v; base[t] = ex; cursor[t] = ex; }
    if (t == 0) base[NB] = E;
}

// ---- pass 1: group edge records by bucket. Per-block LDS hist -> one cursor
// reservation per (block,bucket) -> contiguous runs of 16B records ----
__global__ void k_pass1(const int* __restrict__ src, const int* __restrict__ dst,
                        const float4* __restrict__ summary, int* __restrict__ cursor,
                        float4* __restrict__ records, int E, int NB, int chunk) {
    __shared__ int lh[MAXNB];
    __shared__ int lb[MAXNB];
    int c0 = blockIdx.x * chunk;
    int c1 = min(c0 + chunk, E);
    for (int t = threadIdx.x; t < NB; t += blockDim.x) lh[t] = 0;
    __syncthreads();
    for (int e = c0 + threadIdx.x; e < c1; e += blockDim.x)
        atomicAdd(&lh[dst[e] >> 7], 1);
    __syncthreads();
    for (int t = threadIdx.x; t < NB; t += blockDim.x) {
        int h = lh[t];
        lb[t] = h ? atomicAdd(&cursor[t], h) : 0;
    }
    __syncthreads();
    for (int t = threadIdx.x; t < NB; t += blockDim.x) lh[t] = 0;
    __syncthreads();
    for (int e = c0 + threadIdx.x; e < c1; e += blockDim.x) {
        int s = src[e], dd = dst[e];
        int bk = dd >> 7;
        float4 sm = summary[s];
        unsigned bin = __float_as_uint(sm.z);
        unsigned meta = (unsigned)(dd & (BW - 1)) | (bin << 7);
        int pos = lb[bk] + atomicAdd(&lh[bk], 1);
        records[pos] = make_float4(sm.x, sm.y, __uint_as_float(meta), 0.f);
    }
}

// ---- pass 2: per-bucket LDS accumulate + h2 relu + sorted-batch pooling ----
__global__ void k_pass2(const int* __restrict__ base, const float4* __restrict__ records,
                        const float4* __restrict__ summary, const float2* __restrict__ PQ,
                        const float* __restrict__ b2, const int* __restrict__ batch,
                        float* __restrict__ psum, float* __restrict__ cnt, int N) {
    __shared__ float acc[BW * DH];  // 32 KB
    int d = threadIdx.x & 63;
    int w = threadIdx.x >> 6;  // wave 0..7
    for (int t = threadIdx.x; t < BW * DH; t += blockDim.x) acc[t] = 0.f;
    __syncthreads();
    int b = blockIdx.x;
    int r0 = base[b], r1 = base[b + 1];
    for (int e = r0 + w; e < r1; e += 8) {
        float4 r = records[e];
        unsigned meta = __float_as_uint(r.z);
        int dl = meta & (BW - 1);
        int bin = meta >> 7;
        float2 pq = PQ[bin * DH + d];
        atomicAdd(&acc[(dl << 6) | d], r.x * pq.x + r.y * pq.y);
    }
    __syncthreads();
    // finish: wave w handles nodes [w*16, (w+1)*16) of this bucket
    int n0 = b * BW;
    float bias = b2[d];
    float lsum = 0.f, lcnt = 0.f;
    int cb = -1;
    for (int j = 0; j < 16; ++j) {
        int n = (w << 4) + j;
        int i = n0 + n;
        if (i >= N) break;
        float4 sm = summary[i];
        int bi = __float_as_uint(sm.z);
        float2 pq = PQ[bi * DH + d];
        float g = sm.x * pq.x + sm.y * pq.y;
        float v = fmaxf(sm.y * (acc[(n << 6) | d] + g) + bias, 0.f);
        int bt = batch[i];
        if (bt != cb) {
            if (cb >= 0) {
                atomicAdd(&psum[cb * DH + d], lsum);
                if (d == 0) atomicAdd(&cnt[cb], lcnt);
            }
            cb = bt; lsum = 0.f; lcnt = 0.f;
        }
        lsum += v;
        if (d == 0) lcnt += 1.f;
    }
    if (cb >= 0) {
        atomicAdd(&psum[cb * DH + d], lsum);
        if (d == 0) atomicAdd(&cnt[cb], lcnt);
    }
}

// ---- out[g][o] = (psum[g]/max(cnt,1)) . fcW[:,o] + fcb[o] ----
__global__ void k_out(const float* __restrict__ psum, const float* __restrict__ cnt,
                      const float* __restrict__ fcW, const float* __restrict__ fcb,
                      float* __restrict__ out, int G) {
    int idx = blockIdx.x * blockDim.x + threadIdx.x;
    if (idx >= G * DOUT) return;
    int gi = idx >> 5, o = idx & 31;
    float c = fmaxf(cnt[gi], 1.0f);
    float s = 0.f;
#pragma unroll
    for (int d = 0; d < DH; ++d) s += psum[gi * DH + d] * fcW[d * DOUT + o];
    out[idx] = s / c + fcb[o];
}

static inline size_t pad256(size_t n) { return (n + 255) & ~(size_t)255; }

extern "C" void kernel_launch(void* const* d_in, const int* in_sizes, int n_in,
                              void* d_out, int out_size, void* d_ws, size_t ws_size,
                              hipStream_t stream) {
    const int N = in_sizes[0];
    const int E = in_sizes[1] / 2;
    const int G = out_size / DOUT;
    const int NB = (N + BW - 1) / BW;

    const int* edge = (const int*)d_in[1];
    const int* src = edge;
    const int* dst = edge + E;
    const int* batch = (const int*)d_in[2];
    const float* emb = (const float*)d_in[3];
    const float* W1 = (const float*)d_in[4];
    const float* b1 = (const float*)d_in[5];
    const float* W2 = (const float*)d_in[6];
    const float* b2 = (const float*)d_in[7];
    const float* fcW = (const float*)d_in[8];
    const float* fcb = (const float*)d_in[9];
    float* out = (float*)d_out;

    // workspace layout. Zero region first: counts, S, psum, cnt, bhist.
    char* ws = (char*)d_ws;
    size_t off = 0;
    int* counts = (int*)(ws + off);    off += pad256(N) * 4;
    float* S    = (float*)(ws + off);  off += pad256(N) * 4;
    float* psum = (float*)(ws + off);  off += pad256((size_t)G * DH) * 4;
    float* cnt  = (float*)(ws + off);  off += pad256(G) * 4;
    int* bhist  = (int*)(ws + off);    off += pad256(MAXNB) * 4;
    size_t zero_bytes = off;
    float* dinv  = (float*)(ws + off);  off += pad256(N) * 4;
    float* ew    = (float*)(ws + off);  off += pad256(DH) * 4;
    float* tarr  = (float*)(ws + off);  off += pad256(DH) * 4;
    int* rarr    = (int*)(ws + off);    off += pad256(DH) * 4;
    int* sarr    = (int*)(ws + off);    off += pad256(DH) * 4;
    float2* PQ   = (float2*)(ws + off); off += pad256(NBIN * DH) * 8;
    float4* summary = (float4*)(ws + off); off += pad256(N) * 16;
    int* base    = (int*)(ws + off);    off += pad256(MAXNB + 1) * 4;
    int* cursor  = (int*)(ws + off);    off += pad256(MAXNB) * 4;
    float4* records = (float4*)(ws + off); off += pad256(E) * 16;
    // total ~ 29 MB

    hipMemsetAsync(d_ws, 0, zero_bytes, stream);

    const int B = 256;
    k_count<<<(E + B - 1) / B, B, 0, stream>>>(dst, counts, E);
    k_bhist<<<P1B, 1024, 0, stream>>>(dst, bhist, E, NB);
    k_dinv<<<(N + B - 1) / B, B, 0, stream>>>(counts, dinv, N);
    k_S<<<(E + B - 1) / B, B, 0, stream>>>(src, dst, dinv, S, E);
    k_prep<<<1, DH, 0, stream>>>(emb, W1, b1, ew, tarr, rarr, sarr);
    k_tables<<<NBIN, DH, 0, stream>>>(ew, b1, W2, rarr, sarr, PQ);
    k_node2<<<(N + B - 1) / B, B, 0, stream>>>(dinv, S, tarr, summary, N);
    k_bscan<<<1, MAXNB, 0, stream>>>(bhist, base, cursor, NB, E);
    int chunk = (E + P1B - 1) / P1B;
    k_pass1<<<P1B, 1024, 0, stream>>>(src, dst, summary, cursor, records, E, NB, chunk);
    k_pass2<<<NB, 512, 0, stream>>>(base, records, summary, PQ, b2, batch, psum, cnt, N);
    k_out<<<(G * DOUT + B - 1) / B, B, 0, stream>>>(psum, cnt, fcW, fcb, out, G);
}

// Round 6
// 505.773 us; speedup vs baseline: 1.9477x; 1.9477x over previous
//
#include <hip/hip_runtime.h>
#include <hip/hip_bf16.h>

// GCN fused pipeline for MI355X — bin-sum collapsed edges.
// vocab=1 => h1[i] = relu(embW1*c_i + b1) piecewise-linear in scalar c_i with
// <=65 ReLU activation patterns (bins). g[i] = a_i*P[bin_i] + b_i*Q[bin_i].
// Aggregation: agg_i[d] = sum_beta A_i[beta]*P[beta][d] + B_i[beta]*Q[beta][d],
// where (A_i,B_i) are per-(node,bin) sums of neighbor (a,b) — so each edge costs
// only TWO fp32 atomics into an L2-resident table (compact bins, U << 65).
// Inputs: 0 x[int32 N], 1 edge_index[int32 2*E] (src then dst), 2 batch[int32 N sorted],
// 3 emb[1*64], 4 W1[64*64], 5 b1[64], 6 W2[64*64], 7 b2[64], 8 fcW[64*32], 9 fcb[32].
// Output: [G=64, 32] fp32.

#define DH 64
#define DOUT 32
#define NBIN 65

__global__ void k_count(const int* __restrict__ dst, int* __restrict__ counts, int E) {
    int e = blockIdx.x * blockDim.x + threadIdx.x;
    if (e < E) atomicAdd(&counts[dst[e]], 1);
}

__global__ void k_dinv(const int* __restrict__ counts, float* __restrict__ dinv, int N) {
    int i = blockIdx.x * blockDim.x + threadIdx.x;
    if (i < N) dinv[i] = rsqrtf((float)counts[i] + 1.0f);
}

__global__ void k_S(const int* __restrict__ src, const int* __restrict__ dst,
                    const float* __restrict__ dinv, float* __restrict__ S, int E) {
    int e = blockIdx.x * blockDim.x + threadIdx.x;
    if (e < E) atomicAdd(&S[dst[e]], dinv[src[e]]);
}

// ---- embW1, hinge breakpoints t_k, ranks r_k = #{t<=t_k}, s_k = #{t<t_k} ----
__global__ void k_prep(const float* __restrict__ emb, const float* __restrict__ W1,
                       const float* __restrict__ b1, float* __restrict__ ew,
                       float* __restrict__ tarr, int* __restrict__ rarr,
                       int* __restrict__ sarr) {
    __shared__ float tl[DH];
    int k = threadIdx.x;  // 64 threads
    float s = 0.f;
#pragma unroll
    for (int j = 0; j < DH; ++j) s += emb[j] * W1[j * DH + k];
    float t = (s != 0.f) ? (-b1[k] / s) : INFINITY;
    tl[k] = t;
    ew[k] = s;
    tarr[k] = t;
    __syncthreads();
    int r = 0, ss = 0;
#pragma unroll
    for (int j = 0; j < DH; ++j) { r += (tl[j] <= t); ss += (tl[j] < t); }
    rarr[k] = r;
    sarr[k] = ss;
}

// ---- PQ[beta*DH+d] = (P,Q) tables over ReLU active sets ----
__global__ void k_tables(const float* __restrict__ ew, const float* __restrict__ b1,
                         const float* __restrict__ W2, const int* __restrict__ rarr,
                         const int* __restrict__ sarr, float2* __restrict__ PQ) {
    int beta = blockIdx.x;   // 0..64
    int d = threadIdx.x;     // 0..63
    float p = 0.f, q = 0.f;
    for (int k = 0; k < DH; ++k) {
        float e = ew[k];
        bool act;
        if (e > 0.f) act = (beta >= rarr[k]);
        else if (e < 0.f) act = (beta <= sarr[k]);
        else act = (b1[k] > 0.f);
        if (act) {
            float w = W2[k * DH + d];
            p += e * w;
            q += b1[k] * w;
        }
    }
    PQ[beta * DH + d] = make_float2(p, q);
}

// ---- per-node summary (a_i, b_i), raw bin, used-bin flags ----
__global__ void k_node2(const float* __restrict__ dinv, const float* __restrict__ S,
                        const float* __restrict__ tarr, float2* __restrict__ summary,
                        unsigned char* __restrict__ bin, int* __restrict__ flags, int N) {
    __shared__ float tl[DH];
    if (threadIdx.x < DH) tl[threadIdx.x] = tarr[threadIdx.x];
    __syncthreads();
    int i = blockIdx.x * blockDim.x + threadIdx.x;
    if (i >= N) return;
    float di = dinv[i];
    float c = di * (S[i] + di);
    int b = 0;
#pragma unroll
    for (int j = 0; j < DH; ++j) b += (tl[j] < c);
    summary[i] = make_float2(di * c, di);
    bin[i] = (unsigned char)b;
    flags[b] = 1;  // benign race: same value
}

// ---- compact remap of used bins (any bijection works; prefix order) ----
__global__ void k_remap(const int* __restrict__ flags, int* __restrict__ remap,
                        int* __restrict__ Uptr) {
    if (threadIdx.x == 0) {
        int c = 0;
        for (int b = 0; b < NBIN; ++b) { remap[b] = c; c += (flags[b] != 0); }
        *Uptr = c;
    }
}

__global__ void k_binc(const unsigned char* __restrict__ bin, const int* __restrict__ remap,
                       unsigned char* __restrict__ binc, int N) {
    int i = blockIdx.x * blockDim.x + threadIdx.x;
    if (i < N) binc[i] = (unsigned char)remap[bin[i]];
}

// ---- compact PQ tables: PQc[cidx][d] for used bins only (U*512 bytes, L1-hot) ----
__global__ void k_compact(const int* __restrict__ flags, const int* __restrict__ remap,
                          const float2* __restrict__ PQ, float2* __restrict__ PQc) {
    int beta = blockIdx.x, d = threadIdx.x;
    if (flags[beta]) PQc[remap[beta] * DH + d] = PQ[beta * DH + d];
}

// ---- per-edge: 2 fp32 atomics into binAB[dst][binc_src] (L2-resident) ----
__global__ void k_binagg(const int* __restrict__ src, const int* __restrict__ dst,
                         const float2* __restrict__ summary, const unsigned char* __restrict__ binc,
                         float* __restrict__ binAB, const int* __restrict__ Uptr, int E) {
    int e = blockIdx.x * blockDim.x + threadIdx.x;
    if (e >= E) return;
    int U = *Uptr;
    int s = src[e], dd = dst[e];
    float2 sm = summary[s];
    int c = binc[s];
    float* p = binAB + ((size_t)dd * U + c) * 2;
    atomicAdd(p, sm.x);
    atomicAdd(p + 1, sm.y);
}

// ---- fused: per-node U-term dot with PQc + self term + relu + sorted-batch pooling ----
__global__ void k_agg(const float2* __restrict__ binAB, const float2* __restrict__ summary,
                      const unsigned char* __restrict__ binc, const float2* __restrict__ PQc,
                      const int* __restrict__ Uptr, const float* __restrict__ b2,
                      const int* __restrict__ batch, float* __restrict__ psum,
                      float* __restrict__ cnt, int N, int chunk) {
    int U = *Uptr;
    int d = threadIdx.x & 63;
    int w = threadIdx.x >> 6;  // wave 0..3
    int start = blockIdx.x * chunk;
    int end = min(start + chunk, N);
    float bias = b2[d];
    float lsum = 0.f, lcnt = 0.f;
    int cb = -1;
    for (int i = start + w; i < end; i += 4) {
        const float2* row = binAB + (size_t)i * U;  // wave-uniform addresses
        float agg = 0.f;
        int u = 0;
        for (; u + 4 <= U; u += 4) {
            float2 ab0 = row[u], ab1 = row[u + 1], ab2 = row[u + 2], ab3 = row[u + 3];
            float2 p0 = PQc[(u + 0) * DH + d];
            float2 p1 = PQc[(u + 1) * DH + d];
            float2 p2 = PQc[(u + 2) * DH + d];
            float2 p3 = PQc[(u + 3) * DH + d];
            agg += ab0.x * p0.x + ab0.y * p0.y;
            agg += ab1.x * p1.x + ab1.y * p1.y;
            agg += ab2.x * p2.x + ab2.y * p2.y;
            agg += ab3.x * p3.x + ab3.y * p3.y;
        }
        for (; u < U; ++u) {
            float2 ab = row[u];
            float2 pq = PQc[u * DH + d];
            agg += ab.x * pq.x + ab.y * pq.y;
        }
        float2 sm = summary[i];
        float2 pq = PQc[(int)binc[i] * DH + d];
        float g = sm.x * pq.x + sm.y * pq.y;
        float v = fmaxf(sm.y * (agg + g) + bias, 0.f);
        int bt = batch[i];
        if (bt != cb) {
            if (cb >= 0) {
                atomicAdd(&psum[cb * DH + d], lsum);
                if (d == 0) atomicAdd(&cnt[cb], lcnt);
            }
            cb = bt; lsum = 0.f; lcnt = 0.f;
        }
        lsum += v;
        if (d == 0) lcnt += 1.f;
    }
    if (cb >= 0) {
        atomicAdd(&psum[cb * DH + d], lsum);
        if (d == 0) atomicAdd(&cnt[cb], lcnt);
    }
}

// ---- out[g][o] = (psum[g]/max(cnt,1)) . fcW[:,o] + fcb[o] ----
__global__ void k_out(const float* __restrict__ psum, const float* __restrict__ cnt,
                      const float* __restrict__ fcW, const float* __restrict__ fcb,
                      float* __restrict__ out, int G) {
    int idx = blockIdx.x * blockDim.x + threadIdx.x;
    if (idx >= G * DOUT) return;
    int gi = idx >> 5, o = idx & 31;
    float c = fmaxf(cnt[gi], 1.0f);
    float s = 0.f;
#pragma unroll
    for (int d = 0; d < DH; ++d) s += psum[gi * DH + d] * fcW[d * DOUT + o];
    out[idx] = s / c + fcb[o];
}

static inline size_t pad256(size_t n) { return (n + 255) & ~(size_t)255; }

extern "C" void kernel_launch(void* const* d_in, const int* in_sizes, int n_in,
                              void* d_out, int out_size, void* d_ws, size_t ws_size,
                              hipStream_t stream) {
    const int N = in_sizes[0];
    const int E = in_sizes[1] / 2;
    const int G = out_size / DOUT;

    const int* edge = (const int*)d_in[1];
    const int* src = edge;
    const int* dst = edge + E;
    const int* batch = (const int*)d_in[2];
    const float* emb = (const float*)d_in[3];
    const float* W1 = (const float*)d_in[4];
    const float* b1 = (const float*)d_in[5];
    const float* W2 = (const float*)d_in[6];
    const float* b2 = (const float*)d_in[7];
    const float* fcW = (const float*)d_in[8];
    const float* fcb = (const float*)d_in[9];
    float* out = (float*)d_out;

    // workspace. Zero region first: counts, S, psum, cnt, flags, binAB(worst-case).
    char* ws = (char*)d_ws;
    size_t off = 0;
    int* counts = (int*)(ws + off);    off += pad256(N) * 4;
    float* S    = (float*)(ws + off);  off += pad256(N) * 4;
    float* psum = (float*)(ws + off);  off += pad256((size_t)G * DH) * 4;
    float* cnt  = (float*)(ws + off);  off += pad256(G) * 4;
    int* flags  = (int*)(ws + off);    off += pad256(NBIN) * 4;
    float* binAB = (float*)(ws + off); off += pad256((size_t)N * NBIN * 2) * 4;  // 52 MB worst case
    size_t zero_bytes = off;
    float* dinv  = (float*)(ws + off);  off += pad256(N) * 4;
    float* ew    = (float*)(ws + off);  off += pad256(DH) * 4;
    float* tarr  = (float*)(ws + off);  off += pad256(DH) * 4;
    int* rarr    = (int*)(ws + off);    off += pad256(DH) * 4;
    int* sarr    = (int*)(ws + off);    off += pad256(DH) * 4;
    float2* PQ   = (float2*)(ws + off); off += pad256(NBIN * DH) * 8;
    float2* PQc  = (float2*)(ws + off); off += pad256(NBIN * DH) * 8;
    float2* summary = (float2*)(ws + off); off += pad256(N) * 8;
    unsigned char* bin  = (unsigned char*)(ws + off); off += pad256(N);
    unsigned char* binc = (unsigned char*)(ws + off); off += pad256(N);
    int* remap   = (int*)(ws + off);    off += pad256(NBIN) * 4;
    int* Uptr    = (int*)(ws + off);    off += pad256(1) * 4;
    // total ~ 56 MB

    hipMemsetAsync(d_ws, 0, zero_bytes, stream);

    const int B = 256;
    k_count<<<(E + B - 1) / B, B, 0, stream>>>(dst, counts, E);
    k_dinv<<<(N + B - 1) / B, B, 0, stream>>>(counts, dinv, N);
    k_S<<<(E + B - 1) / B, B, 0, stream>>>(src, dst, dinv, S, E);
    k_prep<<<1, DH, 0, stream>>>(emb, W1, b1, ew, tarr, rarr, sarr);
    k_tables<<<NBIN, DH, 0, stream>>>(ew, b1, W2, rarr, sarr, PQ);
    k_node2<<<(N + B - 1) / B, B, 0, stream>>>(dinv, S, tarr, summary, bin, flags, N);
    k_remap<<<1, 64, 0, stream>>>(flags, remap, Uptr);
    k_binc<<<(N + B - 1) / B, B, 0, stream>>>(bin, remap, binc, N);
    k_compact<<<NBIN, DH, 0, stream>>>(flags, remap, PQ, PQc);
    k_binagg<<<(E + B - 1) / B, B, 0, stream>>>(src, dst, summary, binc, binAB, Uptr, E);
    const int AGG_BLOCKS = 2048;
    int chunk = (N + AGG_BLOCKS - 1) / AGG_BLOCKS;
    k_agg<<<AGG_BLOCKS, B, 0, stream>>>((const float2*)binAB, summary, binc, PQc, Uptr,
                                        b2, batch, psum, cnt, N, chunk);
    k_out<<<(G * DOUT + B - 1) / B, B, 0, stream>>>(psum, cnt, fcW, fcb, out, G);
}

// Round 7
// 256.139 us; speedup vs baseline: 3.8458x; 1.9746x over previous
//
#include <hip/hip_runtime.h>
#include <hip/hip_bf16.h>

// GCN fused pipeline for MI355X — dst-bucket grouping + LDS-local E-passes.
// vocab=1 => h1[i] = relu(embW1*c_i + b1) piecewise-linear in scalar c_i with
// <=65 ReLU patterns (bins). g[i] = a_i*P[bin_i] + b_i*Q[bin_i].
// agg_i[d] = sum_u A_i[u]*P[u][d] + B_i[u]*Q[u][d] with per-(node,bin) sums
// (A,B) accumulated in LDS (2 LDS atomics/edge). NO global atomics on E-scale
// paths (each global atomic costs a 64B HBM line write-through — measured R6).
// Inputs: 0 x[int32 N], 1 edge_index[int32 2*E] (src then dst), 2 batch[int32 N sorted],
// 3 emb[1*64], 4 W1[64*64], 5 b1[64], 6 W2[64*64], 7 b2[64], 8 fcW[64*32], 9 fcb[32].
// Output: [G=64, 32] fp32.

#define DH 64
#define DOUT 32
#define NBIN 65
#define BW 64          // bucket width (nodes per bucket)
#define MAXNB 2048     // max buckets (N <= 131072)
#define SRCM 0x3FFFFFF // 26-bit src mask (N < 2^26)

// ---- bucket histogram of dst ----
__global__ void k_bhist(const int* __restrict__ dst, int* __restrict__ bhist,
                        int E, int NB) {
    __shared__ int lh[MAXNB];
    for (int t = threadIdx.x; t < NB; t += blockDim.x) lh[t] = 0;
    __syncthreads();
    for (int e = blockIdx.x * blockDim.x + threadIdx.x; e < E; e += gridDim.x * blockDim.x)
        atomicAdd(&lh[dst[e] >> 6], 1);
    __syncthreads();
    for (int t = threadIdx.x; t < NB; t += blockDim.x) {
        int h = lh[t];
        if (h) atomicAdd(&bhist[t], h);
    }
}

// ---- exclusive scan of 2048 bucket counts (1024 thr, double buffer) ----
__global__ void k_bscan(const int* __restrict__ bhist, int* __restrict__ base,
                        int* __restrict__ cursor, int NB, int E) {
    __shared__ int buf[2][MAXNB];
    int t = threadIdx.x;  // 1024
    int v0 = (t < NB) ? bhist[t] : 0;
    int v1 = (t + 1024 < NB) ? bhist[t + 1024] : 0;
    buf[0][t] = v0; buf[0][t + 1024] = v1;
    __syncthreads();
    int cur = 0;
    for (int off = 1; off < MAXNB; off <<= 1) {
        int nxt = cur ^ 1;
        int a = buf[cur][t] + ((t >= off) ? buf[cur][t - off] : 0);
        int b = buf[cur][t + 1024] + ((t + 1024 >= off) ? buf[cur][t + 1024 - off] : 0);
        buf[nxt][t] = a; buf[nxt][t + 1024] = b;
        cur = nxt;
        __syncthreads();
    }
    if (t < NB)        { int ex = buf[cur][t] - v0;        base[t] = ex;        cursor[t] = ex; }
    if (t + 1024 < NB) { int ex = buf[cur][t + 1024] - v1; base[t + 1024] = ex; cursor[t + 1024] = ex; }
    if (t == 0) base[NB] = E;
}

// ---- group edges by dst bucket: packed record = src | (dstlow<<26) ----
__global__ void k_group(const int* __restrict__ src, const int* __restrict__ dst,
                        int* __restrict__ cursor, unsigned* __restrict__ rec,
                        int E, int NB, int chunk) {
    __shared__ int lh[MAXNB];
    __shared__ int lb[MAXNB];
    int c0 = blockIdx.x * chunk;
    int c1 = min(c0 + chunk, E);
    for (int t = threadIdx.x; t < NB; t += blockDim.x) lh[t] = 0;
    __syncthreads();
    for (int e = c0 + threadIdx.x; e < c1; e += blockDim.x)
        atomicAdd(&lh[dst[e] >> 6], 1);
    __syncthreads();
    for (int t = threadIdx.x; t < NB; t += blockDim.x) {
        int h = lh[t];
        lb[t] = h ? atomicAdd(&cursor[t], h) : 0;
    }
    __syncthreads();
    for (int t = threadIdx.x; t < NB; t += blockDim.x) lh[t] = 0;
    __syncthreads();
    for (int e = c0 + threadIdx.x; e < c1; e += blockDim.x) {
        int s = src[e], dd = dst[e];
        int bk = dd >> 6;
        int pos = lb[bk] + atomicAdd(&lh[bk], 1);
        rec[pos] = (unsigned)s | ((unsigned)(dd & 63) << 26);
    }
}

// ---- pass A: per-bucket deg count (LDS) -> dinv ----
__global__ void k_passA(const int* __restrict__ base, const unsigned* __restrict__ rec,
                        float* __restrict__ dinv, int N) {
    __shared__ int cl[BW];
    if (threadIdx.x < BW) cl[threadIdx.x] = 0;
    __syncthreads();
    int b = blockIdx.x;
    int r0 = base[b], r1 = base[b + 1];
    for (int e = r0 + threadIdx.x; e < r1; e += blockDim.x)
        atomicAdd(&cl[rec[e] >> 26], 1);
    __syncthreads();
    if (threadIdx.x < BW) {
        int i = b * BW + threadIdx.x;
        if (i < N) dinv[i] = rsqrtf((float)cl[threadIdx.x] + 1.0f);
    }
}

// ---- embW1, hinge breakpoints t_k, ranks ----
__global__ void k_prep(const float* __restrict__ emb, const float* __restrict__ W1,
                       const float* __restrict__ b1, float* __restrict__ ew,
                       float* __restrict__ tarr, int* __restrict__ rarr,
                       int* __restrict__ sarr) {
    __shared__ float tl[DH];
    int k = threadIdx.x;  // 64 threads
    float s = 0.f;
#pragma unroll
    for (int j = 0; j < DH; ++j) s += emb[j] * W1[j * DH + k];
    float t = (s != 0.f) ? (-b1[k] / s) : INFINITY;
    tl[k] = t;
    ew[k] = s;
    tarr[k] = t;
    __syncthreads();
    int r = 0, ss = 0;
#pragma unroll
    for (int j = 0; j < DH; ++j) { r += (tl[j] <= t); ss += (tl[j] < t); }
    rarr[k] = r;
    sarr[k] = ss;
}

// ---- PQ tables over ReLU active sets ----
__global__ void k_tables(const float* __restrict__ ew, const float* __restrict__ b1,
                         const float* __restrict__ W2, const int* __restrict__ rarr,
                         const int* __restrict__ sarr, float2* __restrict__ PQ) {
    int beta = blockIdx.x;   // 0..64
    int d = threadIdx.x;     // 0..63
    float p = 0.f, q = 0.f;
    for (int k = 0; k < DH; ++k) {
        float e = ew[k];
        bool act;
        if (e > 0.f) act = (beta >= rarr[k]);
        else if (e < 0.f) act = (beta <= sarr[k]);
        else act = (b1[k] > 0.f);
        if (act) {
            float w = W2[k * DH + d];
            p += e * w;
            q += b1[k] * w;
        }
    }
    PQ[beta * DH + d] = make_float2(p, q);
}

// ---- pass B: per-bucket S (LDS atomics, dinv[src] from L2) -> summary, rawbin, flags ----
__global__ void k_passB(const int* __restrict__ base, const unsigned* __restrict__ rec,
                        const float* __restrict__ dinv, const float* __restrict__ tarr,
                        float2* __restrict__ summary, unsigned char* __restrict__ rawbin,
                        int* __restrict__ flags, int N) {
    __shared__ float Sl[BW];
    __shared__ float tl[DH];
    if (threadIdx.x < BW) Sl[threadIdx.x] = 0.f;
    if (threadIdx.x < DH) tl[threadIdx.x] = tarr[threadIdx.x];
    __syncthreads();
    int b = blockIdx.x;
    int r0 = base[b], r1 = base[b + 1];
    for (int e = r0 + threadIdx.x; e < r1; e += blockDim.x) {
        unsigned r = rec[e];
        atomicAdd(&Sl[r >> 26], dinv[r & SRCM]);
    }
    __syncthreads();
    if (threadIdx.x < BW) {
        int i = b * BW + threadIdx.x;
        if (i < N) {
            float di = dinv[i];
            float c = di * (Sl[threadIdx.x] + di);
            int bb = 0;
#pragma unroll
            for (int j = 0; j < DH; ++j) bb += (tl[j] < c);
            summary[i] = make_float2(di * c, di);
            rawbin[i] = (unsigned char)bb;
            flags[bb] = 1;  // benign race: same value
        }
    }
}

// ---- compact remap of used bins ----
__global__ void k_remap(const int* __restrict__ flags, int* __restrict__ remap,
                        int* __restrict__ Uptr) {
    if (threadIdx.x == 0) {
        int c = 0;
        for (int b = 0; b < NBIN; ++b) { remap[b] = c; c += (flags[b] != 0); }
        *Uptr = c;
    }
}

__global__ void k_binc(const unsigned char* __restrict__ rawbin, const int* __restrict__ remap,
                       unsigned char* __restrict__ binc, int N) {
    int i = blockIdx.x * blockDim.x + threadIdx.x;
    if (i < N) binc[i] = (unsigned char)remap[rawbin[i]];
}

__global__ void k_compact(const int* __restrict__ flags, const int* __restrict__ remap,
                          const float2* __restrict__ PQ, float2* __restrict__ PQc) {
    int beta = blockIdx.x, d = threadIdx.x;
    if (flags[beta]) PQc[remap[beta] * DH + d] = PQ[beta * DH + d];
}

// ---- pass C: per-bucket bin-sum accumulate (2 LDS atomics/edge) + U-dot +
//      self term + relu + sorted-batch strip pooling. ----
__global__ void k_passC(const int* __restrict__ base, const unsigned* __restrict__ rec,
                        const float2* __restrict__ summary, const unsigned char* __restrict__ binc,
                        const float2* __restrict__ PQc, const int* __restrict__ Uptr,
                        const float* __restrict__ b2, const int* __restrict__ batch,
                        float* __restrict__ psum, float* __restrict__ cnt, int N) {
    __shared__ float AB[BW * NBIN * 2];  // 33.3 KB worst case; only first U columns used
    int U = *Uptr;
    int tid = threadIdx.x;  // 256
    for (int t = tid; t < BW * U * 2; t += blockDim.x) AB[t] = 0.f;
    __syncthreads();
    int b = blockIdx.x;
    int r0 = base[b], r1 = base[b + 1];
    for (int e = r0 + tid; e < r1; e += blockDim.x) {
        unsigned r = rec[e];
        int s = r & SRCM;
        int dl = r >> 26;
        float2 sm = summary[s];
        int c = binc[s];
        float* p = &AB[(dl * U + c) * 2];
        atomicAdd(p, sm.x);
        atomicAdd(p + 1, sm.y);
    }
    __syncthreads();
    // finish: wave w handles nodes [w*16, (w+1)*16) of this bucket
    int d = tid & 63;
    int w = tid >> 6;  // 0..3
    float accv[16];
#pragma unroll
    for (int j = 0; j < 16; ++j) accv[j] = 0.f;
    for (int u = 0; u < U; ++u) {
        float2 pq = PQc[u * DH + d];
#pragma unroll
        for (int j = 0; j < 16; ++j) {
            int n = (w << 4) + j;
            accv[j] += AB[(n * U + u) * 2] * pq.x + AB[(n * U + u) * 2 + 1] * pq.y;
        }
    }
    int n0 = b * BW;
    float bias = b2[d];
    float lsum = 0.f, lcnt = 0.f;
    int cb = -1;
    for (int j = 0; j < 16; ++j) {
        int i = n0 + (w << 4) + j;
        if (i >= N) break;
        float2 sm = summary[i];
        float2 pq = PQc[(int)binc[i] * DH + d];
        float g = sm.x * pq.x + sm.y * pq.y;
        float v = fmaxf(sm.y * (accv[j] + g) + bias, 0.f);
        int bt = batch[i];
        if (bt != cb) {
            if (cb >= 0) {
                atomicAdd(&psum[cb * DH + d], lsum);
                if (d == 0) atomicAdd(&cnt[cb], lcnt);
            }
            cb = bt; lsum = 0.f; lcnt = 0.f;
        }
        lsum += v;
        if (d == 0) lcnt += 1.f;
    }
    if (cb >= 0) {
        atomicAdd(&psum[cb * DH + d], lsum);
        if (d == 0) atomicAdd(&cnt[cb], lcnt);
    }
}

// ---- out[g][o] = (psum[g]/max(cnt,1)) . fcW[:,o] + fcb[o] ----
__global__ void k_out(const float* __restrict__ psum, const float* __restrict__ cnt,
                      const float* __restrict__ fcW, const float* __restrict__ fcb,
                      float* __restrict__ out, int G) {
    int idx = blockIdx.x * blockDim.x + threadIdx.x;
    if (idx >= G * DOUT) return;
    int gi = idx >> 5, o = idx & 31;
    float c = fmaxf(cnt[gi], 1.0f);
    float s = 0.f;
#pragma unroll
    for (int d = 0; d < DH; ++d) s += psum[gi * DH + d] * fcW[d * DOUT + o];
    out[idx] = s / c + fcb[o];
}

static inline size_t pad256(size_t n) { return (n + 255) & ~(size_t)255; }

extern "C" void kernel_launch(void* const* d_in, const int* in_sizes, int n_in,
                              void* d_out, int out_size, void* d_ws, size_t ws_size,
                              hipStream_t stream) {
    const int N = in_sizes[0];
    const int E = in_sizes[1] / 2;
    const int G = out_size / DOUT;
    const int NB = (N + BW - 1) / BW;

    const int* edge = (const int*)d_in[1];
    const int* src = edge;
    const int* dst = edge + E;
    const int* batch = (const int*)d_in[2];
    const float* emb = (const float*)d_in[3];
    const float* W1 = (const float*)d_in[4];
    const float* b1 = (const float*)d_in[5];
    const float* W2 = (const float*)d_in[6];
    const float* b2 = (const float*)d_in[7];
    const float* fcW = (const float*)d_in[8];
    const float* fcb = (const float*)d_in[9];
    float* out = (float*)d_out;

    // workspace. Zero region first: psum, cnt, bhist, flags (small!).
    char* ws = (char*)d_ws;
    size_t off = 0;
    float* psum = (float*)(ws + off);  off += pad256((size_t)G * DH) * 4;
    float* cnt  = (float*)(ws + off);  off += pad256(G) * 4;
    int* bhist  = (int*)(ws + off);    off += pad256(MAXNB) * 4;
    int* flags  = (int*)(ws + off);    off += pad256(NBIN) * 4;
    size_t zero_bytes = off;
    int* base    = (int*)(ws + off);    off += pad256(MAXNB + 1) * 4;
    int* cursor  = (int*)(ws + off);    off += pad256(MAXNB) * 4;
    unsigned* rec = (unsigned*)(ws + off); off += pad256(E) * 4;
    float* dinv  = (float*)(ws + off);  off += pad256(N) * 4;
    float* ew    = (float*)(ws + off);  off += pad256(DH) * 4;
    float* tarr  = (float*)(ws + off);  off += pad256(DH) * 4;
    int* rarr    = (int*)(ws + off);    off += pad256(DH) * 4;
    int* sarr    = (int*)(ws + off);    off += pad256(DH) * 4;
    float2* PQ   = (float2*)(ws + off); off += pad256(NBIN * DH) * 8;
    float2* PQc  = (float2*)(ws + off); off += pad256(NBIN * DH) * 8;
    float2* summary = (float2*)(ws + off); off += pad256(N) * 8;
    unsigned char* rawbin = (unsigned char*)(ws + off); off += pad256(N);
    unsigned char* binc   = (unsigned char*)(ws + off); off += pad256(N);
    int* remap   = (int*)(ws + off);    off += pad256(NBIN) * 4;
    int* Uptr    = (int*)(ws + off);    off += pad256(1) * 4;
    // total ~ 9 MB

    hipMemsetAsync(d_ws, 0, zero_bytes, stream);

    const int B = 256;
    k_bhist<<<120, B, 0, stream>>>(dst, bhist, E, NB);
    k_bscan<<<1, 1024, 0, stream>>>(bhist, base, cursor, NB, E);
    const int GB = 64;  // group blocks: long runs -> line-friendly record writes
    int chunk = (E + GB - 1) / GB;
    k_group<<<GB, 512, 0, stream>>>(src, dst, cursor, rec, E, NB, chunk);
    k_passA<<<NB, B, 0, stream>>>(base, rec, dinv, N);
    k_prep<<<1, DH, 0, stream>>>(emb, W1, b1, ew, tarr, rarr, sarr);
    k_tables<<<NBIN, DH, 0, stream>>>(ew, b1, W2, rarr, sarr, PQ);
    k_passB<<<NB, B, 0, stream>>>(base, rec, dinv, tarr, summary, rawbin, flags, N);
    k_remap<<<1, 64, 0, stream>>>(flags, remap, Uptr);
    k_binc<<<(N + B - 1) / B, B, 0, stream>>>(rawbin, remap, binc, N);
    k_compact<<<NBIN, DH, 0, stream>>>(flags, remap, PQ, PQc);
    k_passC<<<NB, B, 0, stream>>>(base, rec, summary, binc, PQc, Uptr, b2, batch,
                                  psum, cnt, N);
    k_out<<<(G * DOUT + B - 1) / B, B, 0, stream>>>(psum, cnt, fcW, fcb, out, G);
}

// Round 8
// 238.871 us; speedup vs baseline: 4.1239x; 1.0723x over previous
//
#include <hip/hip_runtime.h>
#include <hip/hip_bf16.h>

// GCN fused pipeline for MI355X — dst-bucket grouping + LDS-local E-passes,
// VALU-broadcast finish (v_readlane), raw-bin tables (no compaction).
// vocab=1 => h1[i] = relu(embW1*c_i + b1) piecewise-linear in scalar c_i with
// <=65 ReLU patterns (bins). g[i] = a_i*P[bin_i] + b_i*Q[bin_i].
// agg_i[d] = sum_{used u} A_i[u]*P[u][d] + B_i[u]*Q[u][d], (A,B) accumulated
// in LDS (2 LDS atomics/edge). No global atomics on E-scale paths (R6: each
// global atomic = 64B HBM line write-through). Finish loop broadcasts AB
// columns from registers via readlane instead of uniform ds_read (R7: LDS
// pipe is per-CU and was the 66-of-72 µs bottleneck).
// Inputs: 0 x[int32 N], 1 edge_index[int32 2*E] (src then dst), 2 batch[int32 N sorted],
// 3 emb[1*64], 4 W1[64*64], 5 b1[64], 6 W2[64*64], 7 b2[64], 8 fcW[64*32], 9 fcb[32].
// Output: [G=64, 32] fp32.

#define DH 64
#define DOUT 32
#define NBIN 65
#define BW 64          // bucket width (nodes per bucket)
#define MAXNB 2048     // max buckets (N <= 131072)
#define SRCM 0x3FFFFFF // 26-bit src mask (N < 2^26)

// ---- bucket histogram of dst ----
__global__ void k_bhist(const int* __restrict__ dst, int* __restrict__ bhist,
                        int E, int NB) {
    __shared__ int lh[MAXNB];
    for (int t = threadIdx.x; t < NB; t += blockDim.x) lh[t] = 0;
    __syncthreads();
    for (int e = blockIdx.x * blockDim.x + threadIdx.x; e < E; e += gridDim.x * blockDim.x)
        atomicAdd(&lh[dst[e] >> 6], 1);
    __syncthreads();
    for (int t = threadIdx.x; t < NB; t += blockDim.x) {
        int h = lh[t];
        if (h) atomicAdd(&bhist[t], h);
    }
}

// ---- exclusive scan of 2048 bucket counts (1024 thr, double buffer) ----
__global__ void k_bscan(const int* __restrict__ bhist, int* __restrict__ base,
                        int* __restrict__ cursor, int NB, int E) {
    __shared__ int buf[2][MAXNB];
    int t = threadIdx.x;  // 1024
    int v0 = (t < NB) ? bhist[t] : 0;
    int v1 = (t + 1024 < NB) ? bhist[t + 1024] : 0;
    buf[0][t] = v0; buf[0][t + 1024] = v1;
    __syncthreads();
    int cur = 0;
    for (int off = 1; off < MAXNB; off <<= 1) {
        int nxt = cur ^ 1;
        int a = buf[cur][t] + ((t >= off) ? buf[cur][t - off] : 0);
        int b = buf[cur][t + 1024] + ((t + 1024 >= off) ? buf[cur][t + 1024 - off] : 0);
        buf[nxt][t] = a; buf[nxt][t + 1024] = b;
        cur = nxt;
        __syncthreads();
    }
    if (t < NB)        { int ex = buf[cur][t] - v0;        base[t] = ex;        cursor[t] = ex; }
    if (t + 1024 < NB) { int ex = buf[cur][t + 1024] - v1; base[t + 1024] = ex; cursor[t + 1024] = ex; }
    if (t == 0) base[NB] = E;
}

// ---- group edges by dst bucket: packed record = src | (dstlow<<26) ----
__global__ void k_group(const int* __restrict__ src, const int* __restrict__ dst,
                        int* __restrict__ cursor, unsigned* __restrict__ rec,
                        int E, int NB, int chunk) {
    __shared__ int lh[MAXNB];
    __shared__ int lb[MAXNB];
    int c0 = blockIdx.x * chunk;
    int c1 = min(c0 + chunk, E);
    for (int t = threadIdx.x; t < NB; t += blockDim.x) lh[t] = 0;
    __syncthreads();
    for (int e = c0 + threadIdx.x; e < c1; e += blockDim.x)
        atomicAdd(&lh[dst[e] >> 6], 1);
    __syncthreads();
    for (int t = threadIdx.x; t < NB; t += blockDim.x) {
        int h = lh[t];
        lb[t] = h ? atomicAdd(&cursor[t], h) : 0;
    }
    __syncthreads();
    for (int t = threadIdx.x; t < NB; t += blockDim.x) lh[t] = 0;
    __syncthreads();
    for (int e = c0 + threadIdx.x; e < c1; e += blockDim.x) {
        int s = src[e], dd = dst[e];
        int bk = dd >> 6;
        int pos = lb[bk] + atomicAdd(&lh[bk], 1);
        rec[pos] = (unsigned)s | ((unsigned)(dd & 63) << 26);
    }
}

// ---- pass A: per-bucket deg count (LDS) -> dinv ----
__global__ void k_passA(const int* __restrict__ base, const unsigned* __restrict__ rec,
                        float* __restrict__ dinv, int N) {
    __shared__ int cl[BW];
    if (threadIdx.x < BW) cl[threadIdx.x] = 0;
    __syncthreads();
    int b = blockIdx.x;
    int r0 = base[b], r1 = base[b + 1];
    for (int e = r0 + threadIdx.x; e < r1; e += blockDim.x)
        atomicAdd(&cl[rec[e] >> 26], 1);
    __syncthreads();
    if (threadIdx.x < BW) {
        int i = b * BW + threadIdx.x;
        if (i < N) dinv[i] = rsqrtf((float)cl[threadIdx.x] + 1.0f);
    }
}

// ---- fused prep + PQ tables: 65 blocks x 64 thr; each block recomputes the
// tiny prep (embW1, breakpoints, ranks) locally, block 0 exports tarr ----
__global__ void k_tables(const float* __restrict__ emb, const float* __restrict__ W1,
                         const float* __restrict__ b1, const float* __restrict__ W2,
                         float* __restrict__ tarr, float2* __restrict__ PQ) {
    __shared__ float ewl[DH], tl[DH], bl[DH];
    __shared__ int rl[DH], sl[DH];
    int k = threadIdx.x;  // 64
    float s = 0.f;
#pragma unroll
    for (int j = 0; j < DH; ++j) s += emb[j] * W1[j * DH + k];
    float t = (s != 0.f) ? (-b1[k] / s) : INFINITY;
    ewl[k] = s; tl[k] = t; bl[k] = b1[k];
    __syncthreads();
    int r = 0, ss = 0;
#pragma unroll
    for (int j = 0; j < DH; ++j) { r += (tl[j] <= t); ss += (tl[j] < t); }
    rl[k] = r; sl[k] = ss;
    if (blockIdx.x == 0) tarr[k] = t;
    __syncthreads();
    int beta = blockIdx.x;  // 0..64
    float p = 0.f, q = 0.f;
    for (int kk = 0; kk < DH; ++kk) {
        float e = ewl[kk];
        bool act;
        if (e > 0.f) act = (beta >= rl[kk]);
        else if (e < 0.f) act = (beta <= sl[kk]);
        else act = (bl[kk] > 0.f);
        if (act) {
            float w = W2[kk * DH + k];
            p += e * w;
            q += bl[kk] * w;
        }
    }
    PQ[beta * DH + k] = make_float2(p, q);
}

// ---- pass B: per-bucket S (LDS atomics) -> summary, rawbin, flags ----
__global__ void k_passB(const int* __restrict__ base, const unsigned* __restrict__ rec,
                        const float* __restrict__ dinv, const float* __restrict__ tarr,
                        float2* __restrict__ summary, unsigned char* __restrict__ rawbin,
                        int* __restrict__ flags, int N) {
    __shared__ float Sl[BW];
    __shared__ float tl[DH];
    if (threadIdx.x < BW) Sl[threadIdx.x] = 0.f;
    if (threadIdx.x < DH) tl[threadIdx.x] = tarr[threadIdx.x];
    __syncthreads();
    int b = blockIdx.x;
    int r0 = base[b], r1 = base[b + 1];
    for (int e = r0 + threadIdx.x; e < r1; e += blockDim.x) {
        unsigned r = rec[e];
        atomicAdd(&Sl[r >> 26], dinv[r & SRCM]);
    }
    __syncthreads();
    if (threadIdx.x < BW) {
        int i = b * BW + threadIdx.x;
        if (i < N) {
            float di = dinv[i];
            float c = di * (Sl[threadIdx.x] + di);
            int bb = 0;
#pragma unroll
            for (int j = 0; j < DH; ++j) bb += (tl[j] < c);
            summary[i] = make_float2(di * c, di);
            rawbin[i] = (unsigned char)bb;
            flags[bb] = 1;  // benign race: same value
        }
    }
}

// ---- pass C: per-bucket bin-sum accumulate (2 LDS atomics/edge), then
// register-resident U-dot via readlane broadcast (VALU, not LDS pipe),
// self term + relu + sorted-batch strip pooling. ----
__global__ void k_passC(const int* __restrict__ base, const unsigned* __restrict__ rec,
                        const float2* __restrict__ summary, const unsigned char* __restrict__ rawbin,
                        const float2* __restrict__ PQ, const int* __restrict__ flags,
                        const float* __restrict__ b2, const int* __restrict__ batch,
                        float* __restrict__ psum, float* __restrict__ cnt, int N) {
    __shared__ float AB[BW * NBIN * 2];  // 33,280 B
    __shared__ unsigned char ulist[NBIN];
    __shared__ int Ucnt;
    int tid = threadIdx.x;  // 256
    for (int t = tid; t < BW * NBIN * 2; t += blockDim.x) AB[t] = 0.f;
    // wave 0 builds the used-bin list via ballot (bins 0..63) + bin 64 probe
    if (tid < 64) {
        int act = (flags[tid] != 0);
        unsigned long long mask = __ballot(act);
        int pos = __popcll(mask & ((1ull << tid) - 1ull));
        if (act) ulist[pos] = (unsigned char)tid;
        if (tid == 0) {
            int total = __popcll(mask);
            if (flags[64]) ulist[total++] = 64;
            Ucnt = total;
        }
    }
    __syncthreads();
    // edge accumulate
    int b = blockIdx.x;
    int r0 = base[b], r1 = base[b + 1];
    for (int e = r0 + tid; e < r1; e += blockDim.x) {
        unsigned r = rec[e];
        int s = r & SRCM;
        int dl = r >> 26;
        float2 sm = summary[s];
        int c = rawbin[s];
        float* p = &AB[(dl * NBIN + c) * 2];
        atomicAdd(p, sm.x);
        atomicAdd(p + 1, sm.y);
    }
    __syncthreads();
    int U = Ucnt;
    int d = tid & 63;
    int w = tid >> 6;    // 0..3, wave w owns nodes [w*16, w*16+16)
    int n0b = w << 4;
    // lane d holds bin-column d of its wave's 16 node rows (bins 0..63)
    float2 abr[16];
#pragma unroll
    for (int j = 0; j < 16; ++j)
        abr[j] = *(const float2*)&AB[((n0b + j) * NBIN + d) * 2];
    float accv[16];
#pragma unroll
    for (int j = 0; j < 16; ++j) accv[j] = 0.f;
    for (int uu = 0; uu < U; ++uu) {
        int u = ulist[uu];  // wave-uniform
        float2 pq = PQ[u * DH + d];
        if (u < 64) {
#pragma unroll
            for (int j = 0; j < 16; ++j) {
                float ax = __int_as_float(__builtin_amdgcn_readlane(__float_as_int(abr[j].x), u));
                float ay = __int_as_float(__builtin_amdgcn_readlane(__float_as_int(abr[j].y), u));
                accv[j] += ax * pq.x + ay * pq.y;
            }
        } else {
#pragma unroll
            for (int j = 0; j < 16; ++j) {
                float2 v = *(const float2*)&AB[((n0b + j) * NBIN + 64) * 2];  // uniform broadcast
                accv[j] += v.x * pq.x + v.y * pq.y;
            }
        }
    }
    // finish: self term + relu + sorted-batch strip pooling
    int n0 = b * BW;
    float bias = b2[d];
    float lsum = 0.f, lcnt = 0.f;
    int cb = -1;
    for (int j = 0; j < 16; ++j) {
        int i = n0 + n0b + j;
        if (i >= N) break;
        float2 sm = summary[i];
        float2 pq = PQ[(int)rawbin[i] * DH + d];
        float g = sm.x * pq.x + sm.y * pq.y;
        float v = fmaxf(sm.y * (accv[j] + g) + bias, 0.f);
        int bt = batch[i];
        if (bt != cb) {
            if (cb >= 0) {
                atomicAdd(&psum[cb * DH + d], lsum);
                if (d == 0) atomicAdd(&cnt[cb], lcnt);
            }
            cb = bt; lsum = 0.f; lcnt = 0.f;
        }
        lsum += v;
        if (d == 0) lcnt += 1.f;
    }
    if (cb >= 0) {
        atomicAdd(&psum[cb * DH + d], lsum);
        if (d == 0) atomicAdd(&cnt[cb], lcnt);
    }
}

// ---- out[g][o] = (psum[g]/max(cnt,1)) . fcW[:,o] + fcb[o] ----
__global__ void k_out(const float* __restrict__ psum, const float* __restrict__ cnt,
                      const float* __restrict__ fcW, const float* __restrict__ fcb,
                      float* __restrict__ out, int G) {
    int idx = blockIdx.x * blockDim.x + threadIdx.x;
    if (idx >= G * DOUT) return;
    int gi = idx >> 5, o = idx & 31;
    float c = fmaxf(cnt[gi], 1.0f);
    float s = 0.f;
#pragma unroll
    for (int d = 0; d < DH; ++d) s += psum[gi * DH + d] * fcW[d * DOUT + o];
    out[idx] = s / c + fcb[o];
}

static inline size_t pad256(size_t n) { return (n + 255) & ~(size_t)255; }

extern "C" void kernel_launch(void* const* d_in, const int* in_sizes, int n_in,
                              void* d_out, int out_size, void* d_ws, size_t ws_size,
                              hipStream_t stream) {
    const int N = in_sizes[0];
    const int E = in_sizes[1] / 2;
    const int G = out_size / DOUT;
    const int NB = (N + BW - 1) / BW;

    const int* edge = (const int*)d_in[1];
    const int* src = edge;
    const int* dst = edge + E;
    const int* batch = (const int*)d_in[2];
    const float* emb = (const float*)d_in[3];
    const float* W1 = (const float*)d_in[4];
    const float* b1 = (const float*)d_in[5];
    const float* W2 = (const float*)d_in[6];
    const float* b2 = (const float*)d_in[7];
    const float* fcW = (const float*)d_in[8];
    const float* fcb = (const float*)d_in[9];
    float* out = (float*)d_out;

    // workspace. Zero region first: psum, cnt, bhist, flags (small).
    char* ws = (char*)d_ws;
    size_t off = 0;
    float* psum = (float*)(ws + off);  off += pad256((size_t)G * DH) * 4;
    float* cnt  = (float*)(ws + off);  off += pad256(G) * 4;
    int* bhist  = (int*)(ws + off);    off += pad256(MAXNB) * 4;
    int* flags  = (int*)(ws + off);    off += pad256(NBIN) * 4;
    size_t zero_bytes = off;
    int* base    = (int*)(ws + off);    off += pad256(MAXNB + 1) * 4;
    int* cursor  = (int*)(ws + off);    off += pad256(MAXNB) * 4;
    unsigned* rec = (unsigned*)(ws + off); off += pad256(E) * 4;
    float* dinv  = (float*)(ws + off);  off += pad256(N) * 4;
    float* tarr  = (float*)(ws + off);  off += pad256(DH) * 4;
    float2* PQ   = (float2*)(ws + off); off += pad256(NBIN * DH) * 8;
    float2* summary = (float2*)(ws + off); off += pad256(N) * 8;
    unsigned char* rawbin = (unsigned char*)(ws + off); off += pad256(N);
    // total ~ 8.5 MB

    hipMemsetAsync(d_ws, 0, zero_bytes, stream);

    const int B = 256;
    k_bhist<<<240, B, 0, stream>>>(dst, bhist, E, NB);
    k_bscan<<<1, 1024, 0, stream>>>(bhist, base, cursor, NB, E);
    const int GB = 64;  // few blocks -> long per-(block,bucket) runs -> line-friendly writes
    int chunk = (E + GB - 1) / GB;
    k_group<<<GB, 1024, 0, stream>>>(src, dst, cursor, rec, E, NB, chunk);
    k_passA<<<NB, B, 0, stream>>>(base, rec, dinv, N);
    k_tables<<<NBIN, DH, 0, stream>>>(emb, W1, b1, W2, tarr, PQ);
    k_passB<<<NB, B, 0, stream>>>(base, rec, dinv, tarr, summary, rawbin, flags, N);
    k_passC<<<NB, B, 0, stream>>>(base, rec, summary, rawbin, PQ, flags, b2, batch,
                                  psum, cnt, N);
    k_out<<<(G * DOUT + B - 1) / B, B, 0, stream>>>(psum, cnt, fcW, fcb, out, G);
}